// Round 2
// baseline (103.461 us; speedup 1.0000x reference)
//
#include <hip/hip_runtime.h>
#include <hip/hip_bf16.h>

typedef __bf16 bf16;
typedef __bf16 bf16x4 __attribute__((ext_vector_type(4)));
typedef __bf16 bf16x8 __attribute__((ext_vector_type(8)));
typedef float f32x4 __attribute__((ext_vector_type(4)));

#define S_LEN 2048
#define DHEAD 128
#define QBLK 64
#define KVBLK 64
#define KPAD 136   // 128 + 8 bf16 pad (272B rows, 16B aligned)
#define VPAD 72    // 64 + 8 bf16 pad (144B rows, 16B aligned)
#define PPAD 72

#define SCALE 0.08838834764831845f  // 1/sqrt(128)

// ---------- prepass 1: K fp32 -> bf16 (layout preserved [bh][s][d]) ----------
__global__ void cvt_k(const float* __restrict__ in, bf16* __restrict__ out) {
  const size_t i = ((size_t)blockIdx.x * 256 + threadIdx.x) * 8;
  float4 a = *(const float4*)(in + i);
  float4 b = *(const float4*)(in + i + 4);
  bf16x8 f;
  f[0] = (bf16)a.x; f[1] = (bf16)a.y; f[2] = (bf16)a.z; f[3] = (bf16)a.w;
  f[4] = (bf16)b.x; f[5] = (bf16)b.y; f[6] = (bf16)b.z; f[7] = (bf16)b.w;
  *(bf16x8*)(out + i) = f;
}

// ---------- prepass 2: V fp32 [bh][s][d] -> bf16 transposed [bh][d][s] ----------
__global__ void vtrans(const float* __restrict__ V, bf16* __restrict__ Vt) {
  __shared__ bf16 Vl[64][136];
  const int tid = threadIdx.x;
  const int bh = blockIdx.x;
  const int s0 = blockIdx.y * 64;
  const float* Vp = V + ((size_t)bh * S_LEN + s0) * DHEAD;
  bf16* Vo = Vt + (size_t)bh * DHEAD * S_LEN;

#pragma unroll
  for (int it = 0; it < 4; ++it) {
    int idx = it * 256 + tid;
    int row = idx >> 4, ch = idx & 15;           // 64 rows x 16 chunks of 8
    float4 a = *(const float4*)(Vp + row * DHEAD + ch * 8);
    float4 b = *(const float4*)(Vp + row * DHEAD + ch * 8 + 4);
    bf16x8 f;
    f[0] = (bf16)a.x; f[1] = (bf16)a.y; f[2] = (bf16)a.z; f[3] = (bf16)a.w;
    f[4] = (bf16)b.x; f[5] = (bf16)b.y; f[6] = (bf16)b.z; f[7] = (bf16)b.w;
    *(bf16x8*)&Vl[row][ch * 8] = f;
  }
  __syncthreads();
#pragma unroll
  for (int it = 0; it < 8; ++it) {
    int idx = it * 256 + tid;
    int d = idx >> 4, sc = idx & 15;             // 128 d-rows x 16 s-chunks of 4
    bf16x4 o;
#pragma unroll
    for (int i = 0; i < 4; ++i) o[i] = Vl[sc * 4 + i][d];
    *(bf16x4*)(Vo + (size_t)d * S_LEN + s0 + sc * 4) = o;
  }
}

// ---------- main attention kernel ----------
__launch_bounds__(256, 2)
__global__ void gpsdp_attn(const float* __restrict__ Q,
                           const bf16* __restrict__ Kb,
                           const bf16* __restrict__ Vtb,
                           float* __restrict__ Out) {
  __shared__ bf16 Ks[KVBLK][KPAD];   // K tile [key][d]
  __shared__ bf16 Vt[DHEAD][VPAD];   // V tile transposed [d][key]
  __shared__ bf16 Pw[4][16][PPAD];   // per-wave P tile [q_local][key_local]

  const int tid  = threadIdx.x;
  const int w    = tid >> 6;
  const int lane = tid & 63;
  const int g    = lane >> 4;
  const int c    = lane & 15;

  const int bh = blockIdx.x;        // 0..15  (b*4 + h) — %8 keeps a bh on one XCD
  const int h  = bh & 3;
  const int y  = blockIdx.y;        // 0..31
  const int qt = (y < 16) ? y : 47 - y;   // complementary pairing for causal balance
  const int q0 = qt * QBLK;

  const float inv2sig2_tab[4] = {0.02f, 0.005f, 0.00125f, 0.0003125f};
  const float biasc = inv2sig2_tab[h];

  const size_t base = (size_t)bh * S_LEN * DHEAD;
  const float* Qp = Q + base;
  const bf16*  Kp = Kb + base;
  const bf16*  Vp = Vtb + base;     // [d][s]
  float*       Op = Out + base;

  // ---- hoist Q fragments (fp32 load + cvt, once per block) ----
  bf16x8 qfrag[4];
  {
    const float* qrow = Qp + (size_t)(q0 + 16 * w + c) * DHEAD;
#pragma unroll
    for (int kk = 0; kk < 4; ++kk) {
      const float* p = qrow + kk * 32 + 8 * g;
      float4 a = *(const float4*)p;
      float4 b = *(const float4*)(p + 4);
      bf16x8 f;
      f[0] = (bf16)a.x; f[1] = (bf16)a.y; f[2] = (bf16)a.z; f[3] = (bf16)a.w;
      f[4] = (bf16)b.x; f[5] = (bf16)b.y; f[6] = (bf16)b.z; f[7] = (bf16)b.w;
      qfrag[kk] = f;
    }
  }

  const int qrow_base = q0 + 16 * w + 4 * g;

  float m_run[4], l_run[4];
  f32x4 acc_o[8];
#pragma unroll
  for (int r = 0; r < 4; ++r) { m_run[r] = -3.0e38f; l_run[r] = 0.f; }
#pragma unroll
  for (int n = 0; n < 8; ++n) acc_o[n] = (f32x4){0.f, 0.f, 0.f, 0.f};

  const int ntiles = qt + 1;
  for (int t = 0; t < ntiles; ++t) {
    const int kb = t * KVBLK;

    __syncthreads();

    // ---- stage K tile: bf16, coalesced 16B ----
#pragma unroll
    for (int it = 0; it < 4; ++it) {
      int idx = it * 256 + tid;
      int row = idx >> 4, ch = idx & 15;
      bf16x8 v = *(const bf16x8*)(Kp + (size_t)(kb + row) * DHEAD + ch * 8);
      *(bf16x8*)&Ks[row][ch * 8] = v;
    }
    // ---- stage V tile (already transposed in global): coalesced 16B ----
#pragma unroll
    for (int it = 0; it < 4; ++it) {
      int idx = it * 256 + tid;
      int d = idx >> 3, ch = idx & 7;
      bf16x8 v = *(const bf16x8*)(Vp + (size_t)d * S_LEN + kb + ch * 8);
      *(bf16x8*)&Vt[d][ch * 8] = v;
    }
    __syncthreads();

    // ---- QK^T ----
    f32x4 s[4];
    __builtin_amdgcn_s_setprio(1);
#pragma unroll
    for (int sub = 0; sub < 4; ++sub) {
      f32x4 acc = (f32x4){0.f, 0.f, 0.f, 0.f};
#pragma unroll
      for (int kk = 0; kk < 4; ++kk) {
        bf16x8 kf = *(const bf16x8*)&Ks[sub * 16 + c][kk * 32 + 8 * g];
        acc = __builtin_amdgcn_mfma_f32_16x16x32_bf16(qfrag[kk], kf, acc, 0, 0, 0);
      }
      s[sub] = acc;
    }
    __builtin_amdgcn_s_setprio(0);

    // ---- scale + gaussian bias + causal mask, tile max ----
    float mt[4] = {-3.0e38f, -3.0e38f, -3.0e38f, -3.0e38f};
#pragma unroll
    for (int sub = 0; sub < 4; ++sub) {
      int k = kb + sub * 16 + c;
#pragma unroll
      for (int r = 0; r < 4; ++r) {
        int dqk = (qrow_base + r) - k;
        float fd = (float)dqk;
        float val = (dqk >= 0)
                    ? (s[sub][r] * SCALE + __expf(-fd * fd * biasc))
                    : -3.0e38f;
        s[sub][r] = val;
        mt[r] = fmaxf(mt[r], val);
      }
    }
#pragma unroll
    for (int r = 0; r < 4; ++r) {
      float v = mt[r];
      v = fmaxf(v, __shfl_xor(v, 1));
      v = fmaxf(v, __shfl_xor(v, 2));
      v = fmaxf(v, __shfl_xor(v, 4));
      v = fmaxf(v, __shfl_xor(v, 8));
      mt[r] = v;
    }

    float rescale[4];
#pragma unroll
    for (int r = 0; r < 4; ++r) {
      float m_new = fmaxf(m_run[r], mt[r]);
      rescale[r] = __expf(m_run[r] - m_new);
      m_run[r] = m_new;
    }

    // ---- P = exp(s - m), row sums, P -> per-wave LDS ----
    float rsum[4] = {0.f, 0.f, 0.f, 0.f};
#pragma unroll
    for (int sub = 0; sub < 4; ++sub) {
#pragma unroll
      for (int r = 0; r < 4; ++r) {
        float p = __expf(s[sub][r] - m_run[r]);
        rsum[r] += p;
        Pw[w][4 * g + r][sub * 16 + c] = (bf16)p;
      }
    }
#pragma unroll
    for (int r = 0; r < 4; ++r) {
      float v = rsum[r];
      v += __shfl_xor(v, 1);
      v += __shfl_xor(v, 2);
      v += __shfl_xor(v, 4);
      v += __shfl_xor(v, 8);
      l_run[r] = l_run[r] * rescale[r] + v;
    }

#pragma unroll
    for (int n = 0; n < 8; ++n) {
#pragma unroll
      for (int r = 0; r < 4; ++r) acc_o[n][r] *= rescale[r];
    }

    // ---- PV ----
    __builtin_amdgcn_s_setprio(1);
#pragma unroll
    for (int kc = 0; kc < 2; ++kc) {
      bf16x8 pf = *(const bf16x8*)&Pw[w][c][kc * 32 + 8 * g];
#pragma unroll
      for (int n = 0; n < 8; ++n) {
        bf16x8 vf = *(const bf16x8*)&Vt[n * 16 + c][kc * 32 + 8 * g];
        acc_o[n] = __builtin_amdgcn_mfma_f32_16x16x32_bf16(pf, vf, acc_o[n], 0, 0, 0);
      }
    }
    __builtin_amdgcn_s_setprio(0);
  }

  // ---- epilogue ----
#pragma unroll
  for (int r = 0; r < 4; ++r) {
    float inv_l = 1.0f / l_run[r];
    int q = qrow_base + r;
#pragma unroll
    for (int n = 0; n < 8; ++n) {
      Op[(size_t)q * DHEAD + n * 16 + c] = acc_o[n][r] * inv_l;
    }
  }
}

extern "C" void kernel_launch(void* const* d_in, const int* in_sizes, int n_in,
                              void* d_out, int out_size, void* d_ws, size_t ws_size,
                              hipStream_t stream) {
  const float* Q = (const float*)d_in[0];
  const float* K = (const float*)d_in[1];
  const float* V = (const float*)d_in[2];
  float* Out = (float*)d_out;

  bf16* Kb  = (bf16*)d_ws;                                  // 8 MB
  bf16* Vtb = (bf16*)d_ws + (size_t)16 * S_LEN * DHEAD;     // 8 MB, [bh][d][s]

  // prepass: K -> bf16; V -> bf16 transposed
  cvt_k<<<dim3(2048), 256, 0, stream>>>(K, Kb);
  vtrans<<<dim3(16, 32), 256, 0, stream>>>(V, Vtb);

  dim3 grid(16, 32);
  gpsdp_attn<<<grid, 256, 0, stream>>>(Q, Kb, Vtb, Out);
}

// Round 3
// 97.149 us; speedup vs baseline: 1.0650x; 1.0650x over previous
//
#include <hip/hip_runtime.h>
#include <hip/hip_bf16.h>

typedef __bf16 bf16;
typedef __bf16 bf16x4 __attribute__((ext_vector_type(4)));
typedef __bf16 bf16x8 __attribute__((ext_vector_type(8)));
typedef float f32x4 __attribute__((ext_vector_type(4)));

#define S_LEN 2048
#define DHEAD 128
#define QBLK 64
#define KVBLK 64
#define KPAD 136   // 128 + 8 bf16 pad
#define VPAD 72    // 64 + 8 bf16 pad
#define PPAD 72

#define SCALE 0.08838834764831845f  // 1/sqrt(128)

// ---------- fused prepass: K fp32->bf16 (same layout) + V fp32->bf16 transposed ----------
__global__ void prep(const float* __restrict__ K, const float* __restrict__ V,
                     bf16* __restrict__ Kb, bf16* __restrict__ Vt) {
  __shared__ bf16 Vl[64][136];
  const int tid = threadIdx.x;
  const int bh = blockIdx.x;
  const int s0 = blockIdx.y * 64;
  const float* Kp = K + ((size_t)bh * S_LEN + s0) * DHEAD;
  const float* Vp = V + ((size_t)bh * S_LEN + s0) * DHEAD;
  bf16* Ko = Kb + ((size_t)bh * S_LEN + s0) * DHEAD;
  bf16* Vo = Vt + (size_t)bh * DHEAD * S_LEN;

  // K convert: 64 rows x 128 = 1024 chunks of 8
#pragma unroll
  for (int it = 0; it < 4; ++it) {
    int idx = it * 256 + tid;
    float4 a = *(const float4*)(Kp + idx * 8);
    float4 b = *(const float4*)(Kp + idx * 8 + 4);
    bf16x8 f;
    f[0] = (bf16)a.x; f[1] = (bf16)a.y; f[2] = (bf16)a.z; f[3] = (bf16)a.w;
    f[4] = (bf16)b.x; f[5] = (bf16)b.y; f[6] = (bf16)b.z; f[7] = (bf16)b.w;
    *(bf16x8*)(Ko + idx * 8) = f;
  }

  // V transpose via LDS
#pragma unroll
  for (int it = 0; it < 4; ++it) {
    int idx = it * 256 + tid;
    int row = idx >> 4, ch = idx & 15;
    float4 a = *(const float4*)(Vp + row * DHEAD + ch * 8);
    float4 b = *(const float4*)(Vp + row * DHEAD + ch * 8 + 4);
    bf16x8 f;
    f[0] = (bf16)a.x; f[1] = (bf16)a.y; f[2] = (bf16)a.z; f[3] = (bf16)a.w;
    f[4] = (bf16)b.x; f[5] = (bf16)b.y; f[6] = (bf16)b.z; f[7] = (bf16)b.w;
    *(bf16x8*)&Vl[row][ch * 8] = f;
  }
  __syncthreads();
#pragma unroll
  for (int it = 0; it < 8; ++it) {
    int idx = it * 256 + tid;
    int d = idx >> 4, sc = idx & 15;
    bf16x4 o;
#pragma unroll
    for (int i = 0; i < 4; ++i) o[i] = Vl[sc * 4 + i][d];
    *(bf16x4*)(Vo + (size_t)d * S_LEN + s0 + sc * 4) = o;
  }
}

// ---------- main attention kernel ----------
__launch_bounds__(256, 2)
__global__ void gpsdp_attn(const float* __restrict__ Q,
                           const bf16* __restrict__ Kb,
                           const bf16* __restrict__ Vtb,
                           float* __restrict__ Out) {
  __shared__ bf16 Ks[KVBLK][KPAD];   // K tile [key][d]
  __shared__ bf16 Vt[DHEAD][VPAD];   // V tile transposed [d][key]
  __shared__ bf16 Pw[4][16][PPAD];   // per-wave P tile [q_local][key_local]
  __shared__ float Gt[2048];         // gaussian bias table: Gt[d] = exp(-d^2/(2 sigma^2))

  const int tid  = threadIdx.x;
  const int w    = tid >> 6;
  const int lane = tid & 63;
  const int g    = lane >> 4;
  const int c    = lane & 15;

  const int bh = blockIdx.x;        // b*4 + h
  const int h  = bh & 3;
  const int y  = blockIdx.y;
  const int qt = (y < 16) ? y : 47 - y;
  const int q0 = qt * QBLK;

  const float inv2sig2_tab[4] = {0.02f, 0.005f, 0.00125f, 0.0003125f};
  const float biasc = inv2sig2_tab[h];

  const size_t base = (size_t)bh * S_LEN * DHEAD;
  const float* Qp = Q + base;
  const bf16*  Kp = Kb + base;
  const bf16*  Vp = Vtb + base;     // [d][s]
  float*       Op = Out + base;

  // ---- gaussian table (only d in [0, q0+63] reachable) ----
  const int tabn = q0 + QBLK;
  for (int i = tid; i < tabn; i += 256) {
    float fd = (float)i;
    Gt[i] = __expf(-fd * fd * biasc);
  }

  // ---- hoist Q fragments ----
  bf16x8 qfrag[4];
  {
    const float* qrow = Qp + (size_t)(q0 + 16 * w + c) * DHEAD;
#pragma unroll
    for (int kk = 0; kk < 4; ++kk) {
      const float* p = qrow + kk * 32 + 8 * g;
      float4 a = *(const float4*)p;
      float4 b = *(const float4*)(p + 4);
      bf16x8 f;
      f[0] = (bf16)a.x; f[1] = (bf16)a.y; f[2] = (bf16)a.z; f[3] = (bf16)a.w;
      f[4] = (bf16)b.x; f[5] = (bf16)b.y; f[6] = (bf16)b.z; f[7] = (bf16)b.w;
      qfrag[kk] = f;
    }
  }

  const int qrow_base = q0 + 16 * w + 4 * g;

  float m_run[4], l_run[4];
  f32x4 acc_o[8];
#pragma unroll
  for (int r = 0; r < 4; ++r) { m_run[r] = -3.0e38f; l_run[r] = 0.f; }
#pragma unroll
  for (int n = 0; n < 8; ++n) acc_o[n] = (f32x4){0.f, 0.f, 0.f, 0.f};

  // ---- T14 async-stage: prefetch to regs, commit to LDS late ----
  bf16x8 kreg[4], vreg[4];
  auto prefetch = [&](int kb) {
#pragma unroll
    for (int it = 0; it < 4; ++it) {
      int idx = it * 256 + tid;
      int row = idx >> 4, ch = idx & 15;
      kreg[it] = *(const bf16x8*)(Kp + (size_t)(kb + row) * DHEAD + ch * 8);
    }
#pragma unroll
    for (int it = 0; it < 4; ++it) {
      int idx = it * 256 + tid;
      int d = idx >> 3, ch = idx & 7;
      vreg[it] = *(const bf16x8*)(Vp + (size_t)d * S_LEN + kb + ch * 8);
    }
  };
  auto commit = [&]() {
#pragma unroll
    for (int it = 0; it < 4; ++it) {
      int idx = it * 256 + tid;
      int row = idx >> 4, ch = idx & 15;
      *(bf16x8*)&Ks[row][ch * 8] = kreg[it];
    }
#pragma unroll
    for (int it = 0; it < 4; ++it) {
      int idx = it * 256 + tid;
      int d = idx >> 3, ch = idx & 7;
      *(bf16x8*)&Vt[d][ch * 8] = vreg[it];
    }
  };

  const int ntiles = qt + 1;
  prefetch(0);
  commit();
  __syncthreads();   // publishes tile 0 + Gt

  for (int t = 0; t < ntiles; ++t) {
    const int kb = t * KVBLK;
    if (t + 1 < ntiles) prefetch(kb + KVBLK);   // loads fly under compute

    // ---- QK^T ----
    f32x4 s[4];
    __builtin_amdgcn_s_setprio(1);
#pragma unroll
    for (int sub = 0; sub < 4; ++sub) {
      f32x4 acc = (f32x4){0.f, 0.f, 0.f, 0.f};
#pragma unroll
      for (int kk = 0; kk < 4; ++kk) {
        bf16x8 kf = *(const bf16x8*)&Ks[sub * 16 + c][kk * 32 + 8 * g];
        acc = __builtin_amdgcn_mfma_f32_16x16x32_bf16(qfrag[kk], kf, acc, 0, 0, 0);
      }
      s[sub] = acc;
    }
    __builtin_amdgcn_s_setprio(0);

    // ---- scale + table bias + causal mask, tile max ----
    float mt[4] = {-3.0e38f, -3.0e38f, -3.0e38f, -3.0e38f};
    const int dbase = qrow_base - kb - c;
#pragma unroll
    for (int sub = 0; sub < 4; ++sub) {
#pragma unroll
      for (int r = 0; r < 4; ++r) {
        int dqk = dbase + r - sub * 16;
        float gv = Gt[dqk > 0 ? dqk : 0];
        float val = (dqk >= 0) ? fmaf(s[sub][r], SCALE, gv) : -3.0e38f;
        s[sub][r] = val;
        mt[r] = fmaxf(mt[r], val);
      }
    }
#pragma unroll
    for (int r = 0; r < 4; ++r) {
      float v = mt[r];
      v = fmaxf(v, __shfl_xor(v, 1));
      v = fmaxf(v, __shfl_xor(v, 2));
      v = fmaxf(v, __shfl_xor(v, 4));
      v = fmaxf(v, __shfl_xor(v, 8));
      mt[r] = v;
    }

    // ---- T13 defer-max: rescale only when a row grew past m_run + 8 ----
    bool need = (mt[0] > m_run[0] + 8.f) | (mt[1] > m_run[1] + 8.f) |
                (mt[2] > m_run[2] + 8.f) | (mt[3] > m_run[3] + 8.f);
    if (__any(need)) {
#pragma unroll
      for (int r = 0; r < 4; ++r) {
        float m_new = fmaxf(m_run[r], mt[r]);
        float rs = __expf(m_run[r] - m_new);
        m_run[r] = m_new;
        l_run[r] *= rs;
#pragma unroll
        for (int n = 0; n < 8; ++n) acc_o[n][r] *= rs;
      }
    }

    // ---- P = exp(s - m), per-lane partial sums (reduced once at end) ----
#pragma unroll
    for (int sub = 0; sub < 4; ++sub) {
#pragma unroll
      for (int r = 0; r < 4; ++r) {
        float p = __expf(s[sub][r] - m_run[r]);
        l_run[r] += p;
        Pw[w][4 * g + r][sub * 16 + c] = (bf16)p;
      }
    }

    // ---- PV ----
    __builtin_amdgcn_s_setprio(1);
#pragma unroll
    for (int kc = 0; kc < 2; ++kc) {
      bf16x8 pf = *(const bf16x8*)&Pw[w][c][kc * 32 + 8 * g];
#pragma unroll
      for (int n = 0; n < 8; ++n) {
        bf16x8 vf = *(const bf16x8*)&Vt[n * 16 + c][kc * 32 + 8 * g];
        acc_o[n] = __builtin_amdgcn_mfma_f32_16x16x32_bf16(pf, vf, acc_o[n], 0, 0, 0);
      }
    }
    __builtin_amdgcn_s_setprio(0);

    __syncthreads();                       // all waves done reading tile t
    if (t + 1 < ntiles) commit();          // regs -> LDS (waits on vmcnt)
    __syncthreads();                       // publish tile t+1
  }

  // ---- epilogue: reduce denominator across the 16 row-lanes, store ----
#pragma unroll
  for (int r = 0; r < 4; ++r) {
    float v = l_run[r];
    v += __shfl_xor(v, 1);
    v += __shfl_xor(v, 2);
    v += __shfl_xor(v, 4);
    v += __shfl_xor(v, 8);
    float inv_l = 1.0f / v;
    int q = qrow_base + r;
#pragma unroll
    for (int n = 0; n < 8; ++n) {
      Op[(size_t)q * DHEAD + n * 16 + c] = acc_o[n][r] * inv_l;
    }
  }
}

extern "C" void kernel_launch(void* const* d_in, const int* in_sizes, int n_in,
                              void* d_out, int out_size, void* d_ws, size_t ws_size,
                              hipStream_t stream) {
  const float* Q = (const float*)d_in[0];
  const float* K = (const float*)d_in[1];
  const float* V = (const float*)d_in[2];
  float* Out = (float*)d_out;

  bf16* Kb  = (bf16*)d_ws;                                  // 8 MB
  bf16* Vtb = (bf16*)d_ws + (size_t)16 * S_LEN * DHEAD;     // 8 MB, [bh][d][s]

  prep<<<dim3(16, 32), 256, 0, stream>>>(K, V, Kb, Vtb);

  dim3 grid(16, 32);
  gpsdp_attn<<<grid, 256, 0, stream>>>(Q, Kb, Vtb, Out);
}

// Round 4
// 91.680 us; speedup vs baseline: 1.1285x; 1.0597x over previous
//
#include <hip/hip_runtime.h>
#include <hip/hip_bf16.h>

typedef __bf16 bf16;
typedef __bf16 bf16x4 __attribute__((ext_vector_type(4)));
typedef __bf16 bf16x8 __attribute__((ext_vector_type(8)));
typedef float f32x4 __attribute__((ext_vector_type(4)));

#define S_LEN 2048
#define DHEAD 128
#define QBLK 64
#define KVBLK 64
#define KPAD 136   // 272B row stride -> uniform 8-lane/16B-slot (b128 floor, conflict-free)
#define VPAD 72
#define PPAD 72
#define GTN 320    // gaussian bias support: exp(-320^2/3200) = e^-32 ~ 1e-14, negligible

#define SCALE 0.08838834764831845f  // 1/sqrt(128)

// ---------- fused prepass: K fp32->bf16 (same layout) + V fp32->bf16 transposed ----------
__global__ void prep(const float* __restrict__ K, const float* __restrict__ V,
                     bf16* __restrict__ Kb, bf16* __restrict__ Vt) {
  __shared__ bf16 Vl[64][136];
  const int tid = threadIdx.x;
  const int bh = blockIdx.x;
  const int s0 = blockIdx.y * 64;
  const float* Kp = K + ((size_t)bh * S_LEN + s0) * DHEAD;
  const float* Vp = V + ((size_t)bh * S_LEN + s0) * DHEAD;
  bf16* Ko = Kb + ((size_t)bh * S_LEN + s0) * DHEAD;
  bf16* Vo = Vt + (size_t)bh * DHEAD * S_LEN;

#pragma unroll
  for (int it = 0; it < 4; ++it) {
    int idx = it * 256 + tid;
    float4 a = *(const float4*)(Kp + idx * 8);
    float4 b = *(const float4*)(Kp + idx * 8 + 4);
    bf16x8 f;
    f[0] = (bf16)a.x; f[1] = (bf16)a.y; f[2] = (bf16)a.z; f[3] = (bf16)a.w;
    f[4] = (bf16)b.x; f[5] = (bf16)b.y; f[6] = (bf16)b.z; f[7] = (bf16)b.w;
    *(bf16x8*)(Ko + idx * 8) = f;
  }

#pragma unroll
  for (int it = 0; it < 4; ++it) {
    int idx = it * 256 + tid;
    int row = idx >> 4, ch = idx & 15;
    float4 a = *(const float4*)(Vp + row * DHEAD + ch * 8);
    float4 b = *(const float4*)(Vp + row * DHEAD + ch * 8 + 4);
    bf16x8 f;
    f[0] = (bf16)a.x; f[1] = (bf16)a.y; f[2] = (bf16)a.z; f[3] = (bf16)a.w;
    f[4] = (bf16)b.x; f[5] = (bf16)b.y; f[6] = (bf16)b.z; f[7] = (bf16)b.w;
    *(bf16x8*)&Vl[row][ch * 8] = f;
  }
  __syncthreads();
#pragma unroll
  for (int it = 0; it < 8; ++it) {
    int idx = it * 256 + tid;
    int d = idx >> 4, sc = idx & 15;
    bf16x4 o;
#pragma unroll
    for (int i = 0; i < 4; ++i) o[i] = Vl[sc * 4 + i][d];
    *(bf16x4*)(Vo + (size_t)d * S_LEN + s0 + sc * 4) = o;
  }
}

// ---------- main attention kernel ----------
__launch_bounds__(256, 3)
__global__ void gpsdp_attn(const float* __restrict__ Q,
                           const bf16* __restrict__ Kb,
                           const bf16* __restrict__ Vtb,
                           float* __restrict__ Out) {
  __shared__ bf16 Ks[KVBLK][KPAD];   // 17408 B
  __shared__ bf16 Vt[DHEAD][VPAD];   // 18432 B
  __shared__ bf16 Pw[4][16][PPAD];   //  9216 B
  __shared__ float Gt[GTN];          //  1280 B   -> total 46336 B, 3 blocks/CU

  const int tid  = threadIdx.x;
  const int w    = tid >> 6;
  const int lane = tid & 63;
  const int g    = lane >> 4;
  const int c    = lane & 15;

  const int bh = blockIdx.x;        // b*4 + h
  const int h  = bh & 3;
  const int y  = blockIdx.y;
  const int qt = (y < 16) ? y : 47 - y;   // complementary pairing for causal balance
  const int q0 = qt * QBLK;

  const float inv2sig2_tab[4] = {0.02f, 0.005f, 0.00125f, 0.0003125f};
  const float biasc = inv2sig2_tab[h];

  const size_t base = (size_t)bh * S_LEN * DHEAD;
  const float* Qp = Q + base;
  const bf16*  Kp = Kb + base;
  const bf16*  Vp = Vtb + base;     // [d][s]
  float*       Op = Out + base;

  // ---- gaussian table ----
  for (int i = tid; i < GTN; i += 256) {
    float fd = (float)i;
    Gt[i] = __expf(-fd * fd * biasc);
  }

  // ---- hoist Q fragments ----
  bf16x8 qfrag[4];
  {
    const float* qrow = Qp + (size_t)(q0 + 16 * w + c) * DHEAD;
#pragma unroll
    for (int kk = 0; kk < 4; ++kk) {
      const float* p = qrow + kk * 32 + 8 * g;
      float4 a = *(const float4*)p;
      float4 b = *(const float4*)(p + 4);
      bf16x8 f;
      f[0] = (bf16)a.x; f[1] = (bf16)a.y; f[2] = (bf16)a.z; f[3] = (bf16)a.w;
      f[4] = (bf16)b.x; f[5] = (bf16)b.y; f[6] = (bf16)b.z; f[7] = (bf16)b.w;
      qfrag[kk] = f;
    }
  }

  const int qrow_base = q0 + 16 * w + 4 * g;

  float m_run[4], l_run[4];
  f32x4 acc_o[8];
#pragma unroll
  for (int r = 0; r < 4; ++r) { m_run[r] = -3.0e38f; l_run[r] = 0.f; }
#pragma unroll
  for (int n = 0; n < 8; ++n) acc_o[n] = (f32x4){0.f, 0.f, 0.f, 0.f};

  // ---- async staging: prefetch to regs, commit to LDS late (T14) ----
  bf16x8 kreg[4], vreg[4];
  auto prefetch = [&](int kb) {
#pragma unroll
    for (int it = 0; it < 4; ++it) {
      int idx = it * 256 + tid;
      int row = idx >> 4, ch = idx & 15;
      kreg[it] = *(const bf16x8*)(Kp + (size_t)(kb + row) * DHEAD + ch * 8);
    }
#pragma unroll
    for (int it = 0; it < 4; ++it) {
      int idx = it * 256 + tid;
      int d = idx >> 3, ch = idx & 7;
      vreg[it] = *(const bf16x8*)(Vp + (size_t)d * S_LEN + kb + ch * 8);
    }
  };
  auto commit = [&]() {
#pragma unroll
    for (int it = 0; it < 4; ++it) {
      int idx = it * 256 + tid;
      int row = idx >> 4, ch = idx & 15;
      *(bf16x8*)&Ks[row][ch * 8] = kreg[it];
    }
#pragma unroll
    for (int it = 0; it < 4; ++it) {
      int idx = it * 256 + tid;
      int d = idx >> 3, ch = idx & 7;
      *(bf16x8*)&Vt[d][ch * 8] = vreg[it];
    }
  };

  const int ntiles = qt + 1;
  prefetch(0);
  commit();
  __syncthreads();   // publishes tile 0 + Gt

  for (int t = 0; t < ntiles; ++t) {
    const int kb = t * KVBLK;
    if (t + 1 < ntiles) prefetch(kb + KVBLK);

    // ---- QK^T ----
    f32x4 s[4];
    __builtin_amdgcn_s_setprio(1);
#pragma unroll
    for (int sub = 0; sub < 4; ++sub) {
      f32x4 acc = (f32x4){0.f, 0.f, 0.f, 0.f};
#pragma unroll
      for (int kk = 0; kk < 4; ++kk) {
        bf16x8 kf = *(const bf16x8*)&Ks[sub * 16 + c][kk * 32 + 8 * g];
        acc = __builtin_amdgcn_mfma_f32_16x16x32_bf16(qfrag[kk], kf, acc, 0, 0, 0);
      }
      s[sub] = acc;
    }
    __builtin_amdgcn_s_setprio(0);

    // ---- scale + table bias + causal mask; lane-LOCAL maxima only ----
    float mt[4] = {-3.0e38f, -3.0e38f, -3.0e38f, -3.0e38f};
    const int dbase = qrow_base - kb - c;
#pragma unroll
    for (int sub = 0; sub < 4; ++sub) {
#pragma unroll
      for (int r = 0; r < 4; ++r) {
        int dqk = dbase + r - sub * 16;
        int idx = ((unsigned)dqk < (unsigned)GTN) ? dqk : 0;
        float gv = ((unsigned)dqk < (unsigned)GTN) ? Gt[idx] : 0.0f;
        float val = (dqk >= 0) ? fmaf(s[sub][r], SCALE, gv) : -3.0e38f;
        s[sub][r] = val;
        mt[r] = fmaxf(mt[r], val);
      }
    }

    if (t == 0) {
      // init: full row-max reduce (only once per block)
#pragma unroll
      for (int r = 0; r < 4; ++r) {
        float v = mt[r];
        v = fmaxf(v, __shfl_xor(v, 1));
        v = fmaxf(v, __shfl_xor(v, 2));
        v = fmaxf(v, __shfl_xor(v, 4));
        v = fmaxf(v, __shfl_xor(v, 8));
        m_run[r] = v;
      }
    } else {
      // defer-max: lane-local check; reduce + rescale only when a row grew > THR
      bool grew = (mt[0] > m_run[0] + 8.f) | (mt[1] > m_run[1] + 8.f) |
                  (mt[2] > m_run[2] + 8.f) | (mt[3] > m_run[3] + 8.f);
      if (__any(grew)) {
#pragma unroll
        for (int r = 0; r < 4; ++r) {
          float v = mt[r];
          v = fmaxf(v, __shfl_xor(v, 1));
          v = fmaxf(v, __shfl_xor(v, 2));
          v = fmaxf(v, __shfl_xor(v, 4));
          v = fmaxf(v, __shfl_xor(v, 8));
          float m_new = fmaxf(m_run[r], v);
          float rs = __expf(m_run[r] - m_new);
          m_run[r] = m_new;
          l_run[r] *= rs;
#pragma unroll
          for (int n = 0; n < 8; ++n) acc_o[n][r] *= rs;
        }
      }
    }

    // ---- P = exp(s - m), per-lane partial sums ----
#pragma unroll
    for (int sub = 0; sub < 4; ++sub) {
#pragma unroll
      for (int r = 0; r < 4; ++r) {
        float p = __expf(s[sub][r] - m_run[r]);
        l_run[r] += p;
        Pw[w][4 * g + r][sub * 16 + c] = (bf16)p;
      }
    }

    // ---- PV ----
    __builtin_amdgcn_s_setprio(1);
#pragma unroll
    for (int kc = 0; kc < 2; ++kc) {
      bf16x8 pf = *(const bf16x8*)&Pw[w][c][kc * 32 + 8 * g];
#pragma unroll
      for (int n = 0; n < 8; ++n) {
        bf16x8 vf = *(const bf16x8*)&Vt[n * 16 + c][kc * 32 + 8 * g];
        acc_o[n] = __builtin_amdgcn_mfma_f32_16x16x32_bf16(pf, vf, acc_o[n], 0, 0, 0);
      }
    }
    __builtin_amdgcn_s_setprio(0);

    __syncthreads();
    if (t + 1 < ntiles) commit();
    __syncthreads();
  }

  // ---- epilogue: one denominator reduce, store ----
#pragma unroll
  for (int r = 0; r < 4; ++r) {
    float v = l_run[r];
    v += __shfl_xor(v, 1);
    v += __shfl_xor(v, 2);
    v += __shfl_xor(v, 4);
    v += __shfl_xor(v, 8);
    float inv_l = 1.0f / v;
    int q = qrow_base + r;
#pragma unroll
    for (int n = 0; n < 8; ++n) {
      Op[(size_t)q * DHEAD + n * 16 + c] = acc_o[n][r] * inv_l;
    }
  }
}

extern "C" void kernel_launch(void* const* d_in, const int* in_sizes, int n_in,
                              void* d_out, int out_size, void* d_ws, size_t ws_size,
                              hipStream_t stream) {
  const float* Q = (const float*)d_in[0];
  const float* K = (const float*)d_in[1];
  const float* V = (const float*)d_in[2];
  float* Out = (float*)d_out;

  bf16* Kb  = (bf16*)d_ws;                                  // 8 MB
  bf16* Vtb = (bf16*)d_ws + (size_t)16 * S_LEN * DHEAD;     // 8 MB, [bh][d][s]

  prep<<<dim3(16, 32), 256, 0, stream>>>(K, V, Kb, Vtb);

  dim3 grid(16, 32);
  gpsdp_attn<<<grid, 256, 0, stream>>>(Q, Kb, Vtb, Out);
}